// Round 13
// baseline (685.443 us; speedup 1.0000x reference)
//
#include <hip/hip_runtime.h>

// ---------------------------------------------------------------------------
// GCN stack: 9 layers of  h = relu( Â (h W) + b ),  Â = D^-1/2 (A+I) D^-1/2
//   * Â(HW) == (ÂH)W  -> aggregate at width min(din,dout) per layer
//   * Â identical across layers -> CSR (self-loops folded) built once
// R13: (a) agg inner loop: group-uniform uint4 edge loads (2 broadcast loads
//     per 8 edges, NO ds_bpermute) + 8-multiple padded edge lists (zero-weight
//     pads -> no per-edge guards) + always-prefetch. (b) CSR built directly in
//     sorted+padded order via iperm (edgeperm pass, unsorted edges array, and
//     rowp scan chain all deleted). GEMM/schedule unchanged from R12.
// ---------------------------------------------------------------------------

#define TPB 256

using bf16x8 = __attribute__((ext_vector_type(8))) __bf16;
using f32x4  = __attribute__((ext_vector_type(4))) float;
using f32x2  = __attribute__((ext_vector_type(2))) float;

__device__ __forceinline__ unsigned bf16rne(float x) {
    unsigned u = __float_as_uint(x);
    return (u + 0x7fffu + ((u >> 16) & 1u)) >> 16;
}

// async global->LDS, 16B per lane. l is the WAVE-UNIFORM base; HW adds lane*16.
__device__ __forceinline__ void stage16(const unsigned short* g, unsigned short* l) {
#if __has_builtin(__builtin_amdgcn_global_load_lds)
    __builtin_amdgcn_global_load_lds((const __attribute__((address_space(1))) void*)g,
                                     (__attribute__((address_space(3))) void*)l, 16, 0, 0);
#else
    *(uint4*)((char*)l + (threadIdx.x & 63) * 16) = *(const uint4*)g;
#endif
}

// ---------------- graph prep kernels ----------------

// zero cnt/fill and the padded edge array in one dispatch (grid covers ecap)
__global__ void zinit_kernel(int* cnt, int* fill, unsigned* edges2, int n, int ecap) {
    int i = blockIdx.x * blockDim.x + threadIdx.x;
    if (i < n) { cnt[i] = 0; fill[i] = 0; }
    if (i < ecap) edges2[i] = 0u;               // pad entries: src 0, w +0.0
}

__global__ void count_kernel(const int* __restrict__ dst, int* __restrict__ cnt, int E) {
    int e = blockIdx.x * blockDim.x + threadIdx.x;
    if (e < E) atomicAdd(&cnt[dst[e]], 1);
}

__global__ void dinv_kernel(const int* __restrict__ cnt, float* __restrict__ dinv, int n) {
    int i = blockIdx.x * blockDim.x + threadIdx.x;
    if (i < n) dinv[i] = rsqrtf((float)(cnt[i] + 1));
}

// ---- contention-free counting sort (degree bins 0..63) ----

// Pass A: per-block LDS histogram + local ranks; hb bin-major [64][nb]
__global__ void blockhist_kernel(const int* __restrict__ cnt, int* __restrict__ localRank,
                                 int* __restrict__ hb, int n, int nb) {
    __shared__ int h[64];
    int t = threadIdx.x;
    if (t < 64) h[t] = 0;
    __syncthreads();
    int i = blockIdx.x * TPB + t;
    if (i < n) {
        int d = cnt[i]; if (d > 63) d = 63;
        localRank[i] = atomicAdd(&h[d], 1);      // LDS atomic: fast
    }
    __syncthreads();
    if (t < 64) hb[t * nb + blockIdx.x] = h[t];
}

// Pass B: all-in-LDS scan (one block, coalesced in/out).
__global__ __launch_bounds__(256) void sortscan_kernel(int* __restrict__ hb, int nb) {
    __shared__ int sh[64 * 256];                  // 64 KB, nb <= 256
    __shared__ int tot[64], base[64];
    int t = threadIdx.x;
    int total = 64 * nb;
    for (int i = t; i < total; i += 256) sh[i] = hb[i];
    __syncthreads();
    if (t < 64) {
        int run = 0;
        for (int b = 0; b < nb; b++) {
            int v = sh[t * nb + b];
            sh[t * nb + b] = run;
            run += v;
        }
        tot[t] = run;
    }
    __syncthreads();
    if (t == 0) {
        int acc = 0;
        for (int b = 0; b < 64; b++) { base[b] = acc; acc += tot[b]; }
    }
    __syncthreads();
    for (int i = t; i < total; i += 256) hb[i] = sh[i] + base[i / nb];
}

// Pass C: atomic-free scatter; emits perm, sorted counts, and inverse perm
__global__ void scatter2_kernel(const int* __restrict__ cnt,
                                const int* __restrict__ localRank, const int* __restrict__ hb,
                                int* __restrict__ perm, int* __restrict__ pcnt,
                                int* __restrict__ iperm, int n, int nb) {
    int i = blockIdx.x * TPB + threadIdx.x;
    if (i >= n) return;
    int c = cnt[i];
    int d = c; if (d > 63) d = 63;
    int pos = hb[d * nb + blockIdx.x] + localRank[i];
    perm[pos] = i;
    pcnt[pos] = c;
    iperm[i] = pos;
}

// scan over PADDED degree = ceil((pcnt+1)/8)*8 -> sorted padded CSR offsets
__global__ void scanpad_kernel(const int* __restrict__ pcnt, int* __restrict__ prowp2,
                               int* __restrict__ bsums, int n) {
    __shared__ int sh[TPB];
    int t = threadIdx.x;
    int i = blockIdx.x * TPB + t;
    int v = (i < n) ? ((pcnt[i] + 1 + 7) & ~7) : 0;
    sh[t] = v;
    __syncthreads();
    for (int off = 1; off < TPB; off <<= 1) {
        int x = (t >= off) ? sh[t - off] : 0;
        __syncthreads();
        sh[t] += x;
        __syncthreads();
    }
    if (i < n) prowp2[i] = sh[t] - v;
    if (t == TPB - 1) bsums[blockIdx.x] = sh[t];
}

__global__ void scan2_kernel(int* __restrict__ bsums, int nb) {
    __shared__ int sh[TPB];
    int t = threadIdx.x;
    int v = (t < nb) ? bsums[t] : 0;
    sh[t] = v;
    __syncthreads();
    for (int off = 1; off < TPB; off <<= 1) {
        int x = (t >= off) ? sh[t - off] : 0;
        __syncthreads();
        sh[t] += x;
        __syncthreads();
    }
    if (t < nb) bsums[t] = sh[t] - v;
}

__global__ void scan3_kernel(int* __restrict__ rowp, const int* __restrict__ bsums, int n) {
    int i = blockIdx.x * TPB + threadIdx.x;
    if (i < n) rowp[i] += bsums[blockIdx.x];
}

// real + self edges written DIRECTLY into sorted+padded CSR.
// edge = u16 src | bf16(weight) << 16   (N=50000 < 65536)
__global__ void fillself_kernel(const int* __restrict__ src, const int* __restrict__ dst,
                                const float* __restrict__ dinv,
                                const int* __restrict__ iperm, const int* __restrict__ prowp2,
                                int* __restrict__ fill, const int* __restrict__ cnt,
                                unsigned* __restrict__ edges2, int E, int n) {
    int id = blockIdx.x * blockDim.x + threadIdx.x;
    if (id < E) {
        int s = src[id], d = dst[id];
        int pos = prowp2[iperm[d]] + atomicAdd(&fill[d], 1);
        edges2[pos] = (unsigned)s | (bf16rne(dinv[s] * dinv[d]) << 16);
    } else if (id < E + n) {
        int i = id - E;
        float dv = dinv[i];
        edges2[prowp2[iperm[i]] + cnt[i]] = (unsigned)i | (bf16rne(dv * dv) << 16);
    }
}

// ---------------- weight / input prep ----------------

struct WPtrs { const float* p[8]; };

__global__ void wt_all_kernel(WPtrs wp, unsigned short* __restrict__ Wts) {
    const int cum[9] = {0, 16384, 40960, 90112, 155648, 221184, 286720, 335872, 360448};
    const int Ns[8] = {128, 192, 256, 256, 256, 256, 192, 128};
    const int Ks[8] = {128, 128, 192, 256, 256, 256, 256, 192};
    int id = blockIdx.x * blockDim.x + threadIdx.x;
    if (id >= 360448) return;
    int L = 0;
#pragma unroll
    for (int t = 1; t < 8; t++) if (id >= cum[t]) L = t;
    int lid = id - cum[L];
    int N = Ns[L], K = Ks[L];
    int k = lid / N, n = lid - k * N;
    Wts[cum[L] + n * K + k] = (unsigned short)bf16rne(wp.p[L][lid]);
}

__global__ void cvt_bf16_kernel(const float* __restrict__ in, unsigned short* __restrict__ out,
                                int n4) {
    int i = blockIdx.x * blockDim.x + threadIdx.x;
    if (i >= n4) return;
    float4 v = ((const float4*)in)[i];
    uint2 o;
    o.x = bf16rne(v.x) | (bf16rne(v.y) << 16);
    o.y = bf16rne(v.z) | (bf16rne(v.w) << 16);
    ((uint2*)out)[i] = o;
}

// ---------------- MFMA GEMM (operand-swapped, unchanged) ----------------

__global__ __launch_bounds__(256) void gemm_mfma_kernel(
    const unsigned short* __restrict__ A, const unsigned short* __restrict__ Wt,
    const float* __restrict__ bias, unsigned short* __restrict__ C,
    int M, int K, int Nc, int doBias, int doRelu, int outChunked) {
    __shared__ unsigned short Qb[128 * 64];   // activations (nodes x K-chunk)
    __shared__ unsigned short Pb[128 * 64];   // weights (feats x K-chunk)
    int tid = threadIdx.x;
    int l = tid & 63, w = tid >> 6;
    int node0 = blockIdx.x * 128, feat0 = blockIdx.y * 128;

    f32x4 acc[4][4];
#pragma unroll
    for (int i = 0; i < 4; i++)
#pragma unroll
        for (int j = 0; j < 4; j++) acc[i][j] = (f32x4){0.f, 0.f, 0.f, 0.f};

    const unsigned short* gQ[4];
    const unsigned short* gP[4];
    unsigned short* lQ[4];
    unsigned short* lP[4];
#pragma unroll
    for (int h = 0; h < 4; h++) {
        int slot = tid + h * 256;
        int r = slot >> 3, q = slot & 7;
        int qg = q ^ (r & 7);                  // global-side swizzle
        int nd = node0 + r; if (nd > M - 1) nd = M - 1;
        int ft = feat0 + r; if (ft > Nc - 1) ft = Nc - 1;
        gQ[h] = A + (size_t)nd * K + qg * 8;
        gP[h] = Wt + (size_t)ft * K + qg * 8;
        lQ[h] = Qb + (size_t)(w * 64 + h * 256) * 8;
        lP[h] = Pb + (size_t)(w * 64 + h * 256) * 8;
    }

    int q4 = l >> 4, m16 = l & 15;
    int featHalf = w & 1, nodeHalf = w >> 1;
    int rP0 = featHalf * 64 + m16;
    int rQ0 = nodeHalf * 64 + m16;
    int sw = m16 & 7;

    for (int k0 = 0; k0 < K; k0 += 64) {
        __syncthreads();
#pragma unroll
        for (int h = 0; h < 4; h++) {
            stage16(gQ[h] + k0, lQ[h]);
            stage16(gP[h] + k0, lP[h]);
        }
        __syncthreads();
#pragma unroll
        for (int ko = 0; ko < 2; ko++) {
            bf16x8 pf[4], qf[4];
#pragma unroll
            for (int i = 0; i < 4; i++)
                pf[i] = *(const bf16x8*)(Pb + (rP0 + i * 16) * 64 + ((ko * 4 + q4) ^ sw) * 8);
#pragma unroll
            for (int j = 0; j < 4; j++)
                qf[j] = *(const bf16x8*)(Qb + (rQ0 + j * 16) * 64 + ((ko * 4 + q4) ^ sw) * 8);
#pragma unroll
            for (int i = 0; i < 4; i++)
#pragma unroll
                for (int j = 0; j < 4; j++)
                    acc[i][j] = __builtin_amdgcn_mfma_f32_16x16x32_bf16(pf[i], qf[j],
                                                                        acc[i][j], 0, 0, 0);
        }
    }

    // D layout: col(lane&15)=node, row(quad*4+reg)=feat -> 4 regs = 4 feats
#pragma unroll
    for (int i = 0; i < 4; i++) {
        int gf0 = feat0 + featHalf * 64 + i * 16 + q4 * 4;
        if (gf0 >= Nc) continue;
        float4 bv = make_float4(0.f, 0.f, 0.f, 0.f);
        if (doBias) bv = *(const float4*)(bias + gf0);
        size_t cb = outChunked ? ((size_t)(gf0 >> 5) * ((size_t)M * 32) + (gf0 & 31))
                               : (size_t)gf0;
#pragma unroll
        for (int j = 0; j < 4; j++) {
            int gn = node0 + nodeHalf * 64 + j * 16 + m16;
            if (gn >= M) continue;
            f32x4 v = acc[i][j];
            float x0 = v[0] + bv.x, x1 = v[1] + bv.y;
            float x2 = v[2] + bv.z, x3 = v[3] + bv.w;
            if (doRelu) {
                x0 = fmaxf(x0, 0.f); x1 = fmaxf(x1, 0.f);
                x2 = fmaxf(x2, 0.f); x3 = fmaxf(x3, 0.f);
            }
            uint2 o;
            o.x = bf16rne(x0) | (bf16rne(x1) << 16);
            o.y = bf16rne(x2) | (bf16rne(x3) << 16);
            size_t off = outChunked ? (cb + (size_t)gn * 32) : (cb + (size_t)gn * Nc);
            *(uint2*)(C + off) = o;
        }
    }
}

// out[m] = dot(A[m,0:128], w[0:128])  A bf16 row-major, one wave per row
__global__ void gemv128_bf16_kernel(const unsigned short* __restrict__ A,
                                    const float* __restrict__ w,
                                    float* __restrict__ out, int M) {
    int wid = (blockIdx.x * blockDim.x + threadIdx.x) >> 6;
    int lane = threadIdx.x & 63;
    if (wid >= M) return;
    const unsigned short* a = A + (size_t)wid * 128;
    float a0 = __uint_as_float((unsigned)a[lane] << 16);
    float a1 = __uint_as_float((unsigned)a[lane + 64] << 16);
    float s = a0 * w[lane] + a1 * w[lane + 64];
#pragma unroll
    for (int off = 32; off > 0; off >>= 1) s += __shfl_down(s, off);
    if (lane == 0) out[wid] = s;
}

// ---------------- chunked aggregation, sorted, group-per-node ----------------

// Edge lists padded to multiples of 8 (pad weight = +0.0) and stored in sorted
// node order. Each 8-lane group loads its 8-edge block as TWO group-uniform
// uint4 loads (coalesced broadcast, no ds_bpermute), then issues 8 independent
// row gathers. Next block always prefetched (array has tail slack).
__global__ __launch_bounds__(256) void agg_group_kernel(
    const uint2* __restrict__ in, const int* __restrict__ prowp2,
    const int* __restrict__ pcnt, const int* __restrict__ perm,
    const unsigned* __restrict__ edges2,
    const float* __restrict__ bias, uint2* __restrict__ out,
    int Q, int upx, int ngPerUnit, int NG, int n_nodes, int rowVec2,
    int doBias, int doRelu, int outChunked) {
    int xcd = blockIdx.x & 7;
    int slot = blockIdx.x >> 3;
    int u = slot / ngPerUnit;
    int ngIdx = slot - u * ngPerUnit;
    int unit = xcd * upx + u;
    int chunk = unit / Q;
    int q = unit - chunk * Q;
    int ng = ngIdx * Q + q;
    if (ng >= NG) return;

    int wave = threadIdx.x >> 6;
    int lane = threadIdx.x & 63;
    int group = lane >> 3, fl = lane & 7;
    int i = ng * 32 + wave * 8 + group;        // sorted index
    if (i >= n_nodes) return;

    const uint2* sfl = in + (size_t)chunk * n_nodes * 8 + fl;
    int s0 = prowp2[i];                        // multiple of 8
    int c = pcnt[i] + 1;
    int cpad = (c + 7) & ~7;
    int node = perm[i];
    const uint4* ep = (const uint4*)(edges2 + s0);

    f32x2 aA[4], aB[4];
#pragma unroll
    for (int k = 0; k < 4; k++) { aA[k] = (f32x2){0.f, 0.f}; aB[k] = (f32x2){0.f, 0.f}; }

    uint4 ea = ep[0], eb = ep[1];              // group-uniform broadcast loads
    for (int base = 0; base < cpad; base += 8) {
        uint4 na = ep[2], nb = ep[3];          // always-prefetch (tail slack)
        ep += 2;
        unsigned e[8] = {ea.x, ea.y, ea.z, ea.w, eb.x, eb.y, eb.z, eb.w};
        uint2 p[8];
#pragma unroll
        for (int j = 0; j < 8; j++) p[j] = sfl[(size_t)(e[j] & 0xffffu) * 8];
#pragma unroll
        for (int j = 0; j < 8; j++) {
            float wgt = __uint_as_float(e[j] & 0xffff0000u);  // pad: +0.0
            int k = j & 3;
            f32x2 v0 = {__uint_as_float(p[j].x << 16),
                        __uint_as_float(p[j].x & 0xffff0000u)};
            f32x2 v1 = {__uint_as_float(p[j].y << 16),
                        __uint_as_float(p[j].y & 0xffff0000u)};
            f32x2 w2 = {wgt, wgt};
            aA[k] += w2 * v0;
            aB[k] += w2 * v1;
        }
        ea = na; eb = nb;
    }
    f32x2 sA = (aA[0] + aA[1]) + (aA[2] + aA[3]);
    f32x2 sB = (aB[0] + aB[1]) + (aB[2] + aB[3]);

    if (doBias) {
        float4 bb = ((const float4*)bias)[chunk * 8 + fl];
        sA += (f32x2){bb.x, bb.y};
        sB += (f32x2){bb.z, bb.w};
    }
    if (doRelu) {
        sA[0] = fmaxf(sA[0], 0.f); sA[1] = fmaxf(sA[1], 0.f);
        sB[0] = fmaxf(sB[0], 0.f); sB[1] = fmaxf(sB[1], 0.f);
    }
    uint2 o;
    o.x = bf16rne(sA[0]) | (bf16rne(sA[1]) << 16);
    o.y = bf16rne(sB[0]) | (bf16rne(sB[1]) << 16);
    size_t oi = outChunked ? ((size_t)chunk * n_nodes * 8 + (size_t)node * 8 + fl)
                           : ((size_t)node * rowVec2 + chunk * 8 + fl);
    out[oi] = o;
}

// width-1 aggregation, fp32, sorted CSR: one thread per sorted node
__global__ void agg1_kernel(const float* __restrict__ in, const int* __restrict__ prowp2,
                            const int* __restrict__ pcnt, const int* __restrict__ perm,
                            const unsigned* __restrict__ edges2,
                            const float* __restrict__ bias, float* __restrict__ out,
                            int n_nodes) {
    int n = blockIdx.x * blockDim.x + threadIdx.x;
    if (n >= n_nodes) return;
    float acc = 0.f;
    int s0 = prowp2[n];
    int c = pcnt[n] + 1;
    for (int j = 0; j < c; j++) {
        unsigned e = edges2[s0 + j];
        acc += __uint_as_float(e & 0xffff0000u) * in[e & 0xffffu];
    }
    acc += bias[0];
    out[perm[n]] = acc;
}

// ---------------- host launcher ----------------

extern "C" void kernel_launch(void* const* d_in, const int* in_sizes, int n_in,
                              void* d_out, int out_size, void* d_ws, size_t ws_size,
                              hipStream_t stream) {
    const float* x = (const float*)d_in[0];
    const int* ei = (const int*)d_in[1];
    const int Nn = in_sizes[0] / 128;      // 50000
    const int E = in_sizes[1] / 2;         // 800000
    const int* src = ei;
    const int* dst = ei + E;
    const int ecap = E + 8 * Nn + 64;      // padded CSR upper bound + slack

    char* ws = (char*)d_ws;
    size_t off = 0;
    auto alloc = [&](size_t bytes) -> char* {
        char* p = ws + off;
        off = (off + bytes + 255) & ~(size_t)255;
        return p;
    };
    int* cnt = (int*)alloc((size_t)Nn * 4);
    int* fill = (int*)alloc((size_t)Nn * 4);
    int* bsums = (int*)alloc(1024);
    float* dinv = (float*)alloc((size_t)Nn * 4);
    int* localRank = (int*)alloc((size_t)Nn * 4);
    int* hb = (int*)alloc((size_t)64 * 256 * 4);     // [64][nb], nb<=256
    int* perm = (int*)alloc((size_t)Nn * 4);
    int* pcnt = (int*)alloc((size_t)Nn * 4);
    int* iperm = (int*)alloc((size_t)Nn * 4);
    int* prowp2 = (int*)alloc((size_t)Nn * 4);
    unsigned* edges2 = (unsigned*)alloc((size_t)ecap * 4);
    unsigned short* T = (unsigned short*)alloc((size_t)Nn * 256 * 2);
    unsigned short* H = (unsigned short*)alloc((size_t)Nn * 256 * 2);
    unsigned short* Bx = (unsigned short*)alloc((size_t)Nn * 128 * 2);
    float* F = (float*)alloc((size_t)Nn * 4);
    unsigned short* Wts = (unsigned short*)alloc((size_t)400000 * 2);
    (void)ws_size;

    const int dims[9][2] = {{128,128},{128,192},{192,256},{256,256},{256,256},
                            {256,256},{256,192},{192,128},{128,1}};
    unsigned short* Wt[8];
    {
        size_t o = 0;
        for (int i = 0; i < 8; i++) { Wt[i] = Wts + o; o += (size_t)dims[i][0] * dims[i][1]; }
    }

    int nbN = (Nn + TPB - 1) / TPB;        // 196
    int nbE = (E + TPB - 1) / TPB;
    int nbEN = (E + Nn + TPB - 1) / TPB;
    int nbC = (ecap + TPB - 1) / TPB;

    // ---- graph prep: degree sort + direct sorted/padded CSR build ----
    zinit_kernel<<<nbC, TPB, 0, stream>>>(cnt, fill, edges2, Nn, ecap);
    count_kernel<<<nbE, TPB, 0, stream>>>(dst, cnt, E);
    dinv_kernel<<<nbN, TPB, 0, stream>>>(cnt, dinv, Nn);
    blockhist_kernel<<<nbN, TPB, 0, stream>>>(cnt, localRank, hb, Nn, nbN);
    sortscan_kernel<<<1, 256, 0, stream>>>(hb, nbN);
    scatter2_kernel<<<nbN, TPB, 0, stream>>>(cnt, localRank, hb, perm, pcnt, iperm,
                                             Nn, nbN);
    scanpad_kernel<<<nbN, TPB, 0, stream>>>(pcnt, prowp2, bsums, Nn);
    scan2_kernel<<<1, TPB, 0, stream>>>(bsums, nbN);
    scan3_kernel<<<nbN, TPB, 0, stream>>>(prowp2, bsums, Nn);
    fillself_kernel<<<nbEN, TPB, 0, stream>>>(src, dst, dinv, iperm, prowp2, fill, cnt,
                                              edges2, E, Nn);

    // ---- weight transpose (one dispatch) + input convert ----
    WPtrs wp;
    for (int i = 0; i < 8; i++) wp.p[i] = (const float*)d_in[2 + 2 * i];
    wt_all_kernel<<<(360448 + TPB - 1) / TPB, TPB, 0, stream>>>(wp, Wts);
    cvt_bf16_kernel<<<(Nn * 32 + TPB - 1) / TPB, TPB, 0, stream>>>(x, Bx, Nn * 32);

    auto gemm = [&](const unsigned short* A, int i, unsigned short* C, int K, int Nc,
                    int doBias, int doRelu, int outChunked) {
        const float* b = (const float*)d_in[3 + 2 * i];
        dim3 grid((Nn + 127) / 128, (Nc + 127) / 128);   // x: nodes, y: feats
        gemm_mfma_kernel<<<grid, 256, 0, stream>>>(A, Wt[i], b, C, Nn, K, Nc,
                                                   doBias, doRelu, outChunked);
    };
    int NG = (Nn + 31) / 32;
    auto agg = [&](const unsigned short* inb, unsigned short* outb, int w, int i,
                   int doBias, int doRelu, int outChunked) {
        int nch = w / 32;
        int Q = (nch == 8) ? 1 : (nch == 6) ? 4 : 2;     // nch*Q % 8 == 0
        int upx = nch * Q / 8;
        int ngPerUnit = (NG + Q - 1) / Q;
        int blocksPerXcd = upx * ngPerUnit;
        const float* b = (const float*)d_in[3 + 2 * i];
        agg_group_kernel<<<blocksPerXcd * 8, 256, 0, stream>>>(
            (const uint2*)inb, prowp2, pcnt, perm, edges2, b, (uint2*)outb,
            Q, upx, ngPerUnit, NG, Nn, w / 4, doBias, doRelu, outChunked);
    };

    // layout chain: GEMM in=row, out=chunked (except G2: row); agg in=chunked,
    // out=row (except A0: chunked, feeds A1)
    gemm(Bx, 0, T, 128, 128, 0, 0, 1);      // G0: t = x@W0          -> T chunked
    agg(T, H, 128, 0, 1, 1, 1);             // A0: h1 = At+b0 relu   -> H chunked
    agg(H, T, 128, 1, 0, 0, 0);             // A1: u = A h1          -> T row
    gemm(T, 1, H, 128, 192, 1, 1, 1);       // G1: h2 = u@W1+b1 relu -> H chunked
    agg(H, T, 192, 2, 0, 0, 0);             // A2: u = A h2          -> T row
    gemm(T, 2, H, 192, 256, 1, 1, 0);       // G2: h3 = u@W2+b2 relu -> H row
    gemm(H, 3, T, 256, 256, 0, 0, 1);       // G3: t = h3@W3         -> T chunked
    agg(T, H, 256, 3, 1, 1, 0);             // A3: h4 = At+b3 relu   -> H row
    gemm(H, 4, T, 256, 256, 0, 0, 1);       // G4: t = h4@W4         -> T chunked
    agg(T, H, 256, 4, 1, 0, 0);             // A4: h5 = At+b4        -> H row
    gemm(H, 5, T, 256, 256, 0, 0, 1);       // G5: t = h5@W5         -> T chunked
    agg(T, H, 256, 5, 1, 1, 0);             // A5: h6 = At+b5 relu   -> H row
    gemm(H, 6, T, 256, 192, 0, 0, 1);       // G6: t = h6@W6         -> T chunked
    agg(T, H, 192, 6, 1, 1, 0);             // A6: h7 = At+b6 relu   -> H row
    gemm(H, 7, T, 192, 128, 0, 0, 1);       // G7: t = h7@W7         -> T chunked
    agg(T, H, 128, 7, 1, 1, 0);             // A7: h8 = At+b7 relu   -> H row
    gemv128_bf16_kernel<<<(Nn + 3) / 4, 256, 0, stream>>>(H, (const float*)d_in[2 + 16],
                                                          F, Nn);
    agg1_kernel<<<nbN, TPB, 0, stream>>>(F, prowp2, pcnt, perm, edges2,
                                         (const float*)d_in[3 + 16], (float*)d_out, Nn);
}

// Round 14
// 659.041 us; speedup vs baseline: 1.0401x; 1.0401x over previous
//
#include <hip/hip_runtime.h>

// ---------------------------------------------------------------------------
// GCN stack: 9 layers of  h = relu( Â (h W) + b ),  Â = D^-1/2 (A+I) D^-1/2
//   * Â(HW) == (ÂH)W  -> aggregate at width min(din,dout) per layer
//   * Â identical across layers -> CSR (self-loops folded) built once
// R14: agg loop reverted to R12's measured-best form (shfl broadcast, dense
//     CSR, guards) — R13 showed agg is MEMORY-side bound: padding grew the
//     edge stream 3.4->4.25 MB and FETCH rose 45->53 MB (slice eviction);
//     instruction savings were hidden under memory latency. Kept R13's
//     direct-sorted CSR build; dinv folded into blockhist; minimal zinit.
// ---------------------------------------------------------------------------

#define TPB 256

using bf16x8 = __attribute__((ext_vector_type(8))) __bf16;
using f32x4  = __attribute__((ext_vector_type(4))) float;
using f32x2  = __attribute__((ext_vector_type(2))) float;

__device__ __forceinline__ unsigned bf16rne(float x) {
    unsigned u = __float_as_uint(x);
    return (u + 0x7fffu + ((u >> 16) & 1u)) >> 16;
}

// async global->LDS, 16B per lane. l is the WAVE-UNIFORM base; HW adds lane*16.
__device__ __forceinline__ void stage16(const unsigned short* g, unsigned short* l) {
#if __has_builtin(__builtin_amdgcn_global_load_lds)
    __builtin_amdgcn_global_load_lds((const __attribute__((address_space(1))) void*)g,
                                     (__attribute__((address_space(3))) void*)l, 16, 0, 0);
#else
    *(uint4*)((char*)l + (threadIdx.x & 63) * 16) = *(const uint4*)g;
#endif
}

// ---------------- graph prep kernels ----------------

__global__ void zinit_kernel(int* cnt, int* fill, int n) {
    int i = blockIdx.x * blockDim.x + threadIdx.x;
    if (i < n) { cnt[i] = 0; fill[i] = 0; }
}

__global__ void count_kernel(const int* __restrict__ dst, int* __restrict__ cnt, int E) {
    int e = blockIdx.x * blockDim.x + threadIdx.x;
    if (e < E) atomicAdd(&cnt[dst[e]], 1);
}

// ---- contention-free counting sort (degree bins 0..63) ----

// Pass A: per-block LDS histogram + local ranks; hb bin-major [64][nb].
// Also emits dinv (cnt is final here).
__global__ void blockhist_kernel(const int* __restrict__ cnt, int* __restrict__ localRank,
                                 int* __restrict__ hb, float* __restrict__ dinv,
                                 int n, int nb) {
    __shared__ int h[64];
    int t = threadIdx.x;
    if (t < 64) h[t] = 0;
    __syncthreads();
    int i = blockIdx.x * TPB + t;
    if (i < n) {
        int c = cnt[i];
        dinv[i] = rsqrtf((float)(c + 1));
        int d = c; if (d > 63) d = 63;
        localRank[i] = atomicAdd(&h[d], 1);      // LDS atomic: fast
    }
    __syncthreads();
    if (t < 64) hb[t * nb + blockIdx.x] = h[t];
}

// Pass B: all-in-LDS scan (one block, coalesced in/out).
__global__ __launch_bounds__(256) void sortscan_kernel(int* __restrict__ hb, int nb) {
    __shared__ int sh[64 * 256];                  // 64 KB, nb <= 256
    __shared__ int tot[64], base[64];
    int t = threadIdx.x;
    int total = 64 * nb;
    for (int i = t; i < total; i += 256) sh[i] = hb[i];
    __syncthreads();
    if (t < 64) {
        int run = 0;
        for (int b = 0; b < nb; b++) {
            int v = sh[t * nb + b];
            sh[t * nb + b] = run;
            run += v;
        }
        tot[t] = run;
    }
    __syncthreads();
    if (t == 0) {
        int acc = 0;
        for (int b = 0; b < 64; b++) { base[b] = acc; acc += tot[b]; }
    }
    __syncthreads();
    for (int i = t; i < total; i += 256) hb[i] = sh[i] + base[i / nb];
}

// Pass C: atomic-free scatter; emits perm, sorted counts, inverse perm
__global__ void scatter2_kernel(const int* __restrict__ cnt,
                                const int* __restrict__ localRank, const int* __restrict__ hb,
                                int* __restrict__ perm, int* __restrict__ pcnt,
                                int* __restrict__ iperm, int n, int nb) {
    int i = blockIdx.x * TPB + threadIdx.x;
    if (i >= n) return;
    int c = cnt[i];
    int d = c; if (d > 63) d = 63;
    int pos = hb[d * nb + blockIdx.x] + localRank[i];
    perm[pos] = i;
    pcnt[pos] = c;
    iperm[i] = pos;
}

// scan over sorted degree = pcnt+1 -> dense sorted CSR offsets
__global__ void scan1_kernel(const int* __restrict__ pcnt, int* __restrict__ prowp2,
                             int* __restrict__ bsums, int n) {
    __shared__ int sh[TPB];
    int t = threadIdx.x;
    int i = blockIdx.x * TPB + t;
    int v = (i < n) ? (pcnt[i] + 1) : 0;
    sh[t] = v;
    __syncthreads();
    for (int off = 1; off < TPB; off <<= 1) {
        int x = (t >= off) ? sh[t - off] : 0;
        __syncthreads();
        sh[t] += x;
        __syncthreads();
    }
    if (i < n) prowp2[i] = sh[t] - v;
    if (t == TPB - 1) bsums[blockIdx.x] = sh[t];
}

__global__ void scan2_kernel(int* __restrict__ bsums, int nb) {
    __shared__ int sh[TPB];
    int t = threadIdx.x;
    int v = (t < nb) ? bsums[t] : 0;
    sh[t] = v;
    __syncthreads();
    for (int off = 1; off < TPB; off <<= 1) {
        int x = (t >= off) ? sh[t - off] : 0;
        __syncthreads();
        sh[t] += x;
        __syncthreads();
    }
    if (t < nb) bsums[t] = sh[t] - v;
}

__global__ void scan3_kernel(int* __restrict__ rowp, const int* __restrict__ bsums, int n) {
    int i = blockIdx.x * TPB + threadIdx.x;
    if (i < n) rowp[i] += bsums[blockIdx.x];
}

// real + self edges written DIRECTLY into sorted dense CSR.
// edge = u16 src | bf16(weight) << 16   (N=50000 < 65536)
__global__ void fillself_kernel(const int* __restrict__ src, const int* __restrict__ dst,
                                const float* __restrict__ dinv,
                                const int* __restrict__ iperm, const int* __restrict__ prowp2,
                                int* __restrict__ fill, const int* __restrict__ cnt,
                                unsigned* __restrict__ edges2, int E, int n) {
    int id = blockIdx.x * blockDim.x + threadIdx.x;
    if (id < E) {
        int s = src[id], d = dst[id];
        int pos = prowp2[iperm[d]] + atomicAdd(&fill[d], 1);
        edges2[pos] = (unsigned)s | (bf16rne(dinv[s] * dinv[d]) << 16);
    } else if (id < E + n) {
        int i = id - E;
        float dv = dinv[i];
        edges2[prowp2[iperm[i]] + cnt[i]] = (unsigned)i | (bf16rne(dv * dv) << 16);
    }
}

// ---------------- weight / input prep ----------------

struct WPtrs { const float* p[8]; };

__global__ void wt_all_kernel(WPtrs wp, unsigned short* __restrict__ Wts) {
    const int cum[9] = {0, 16384, 40960, 90112, 155648, 221184, 286720, 335872, 360448};
    const int Ns[8] = {128, 192, 256, 256, 256, 256, 192, 128};
    const int Ks[8] = {128, 128, 192, 256, 256, 256, 256, 192};
    int id = blockIdx.x * blockDim.x + threadIdx.x;
    if (id >= 360448) return;
    int L = 0;
#pragma unroll
    for (int t = 1; t < 8; t++) if (id >= cum[t]) L = t;
    int lid = id - cum[L];
    int N = Ns[L], K = Ks[L];
    int k = lid / N, n = lid - k * N;
    Wts[cum[L] + n * K + k] = (unsigned short)bf16rne(wp.p[L][lid]);
}

__global__ void cvt_bf16_kernel(const float* __restrict__ in, unsigned short* __restrict__ out,
                                int n4) {
    int i = blockIdx.x * blockDim.x + threadIdx.x;
    if (i >= n4) return;
    float4 v = ((const float4*)in)[i];
    uint2 o;
    o.x = bf16rne(v.x) | (bf16rne(v.y) << 16);
    o.y = bf16rne(v.z) | (bf16rne(v.w) << 16);
    ((uint2*)out)[i] = o;
}

// ---------------- MFMA GEMM (operand-swapped, unchanged) ----------------

__global__ __launch_bounds__(256) void gemm_mfma_kernel(
    const unsigned short* __restrict__ A, const unsigned short* __restrict__ Wt,
    const float* __restrict__ bias, unsigned short* __restrict__ C,
    int M, int K, int Nc, int doBias, int doRelu, int outChunked) {
    __shared__ unsigned short Qb[128 * 64];   // activations (nodes x K-chunk)
    __shared__ unsigned short Pb[128 * 64];   // weights (feats x K-chunk)
    int tid = threadIdx.x;
    int l = tid & 63, w = tid >> 6;
    int node0 = blockIdx.x * 128, feat0 = blockIdx.y * 128;

    f32x4 acc[4][4];
#pragma unroll
    for (int i = 0; i < 4; i++)
#pragma unroll
        for (int j = 0; j < 4; j++) acc[i][j] = (f32x4){0.f, 0.f, 0.f, 0.f};

    const unsigned short* gQ[4];
    const unsigned short* gP[4];
    unsigned short* lQ[4];
    unsigned short* lP[4];
#pragma unroll
    for (int h = 0; h < 4; h++) {
        int slot = tid + h * 256;
        int r = slot >> 3, q = slot & 7;
        int qg = q ^ (r & 7);                  // global-side swizzle
        int nd = node0 + r; if (nd > M - 1) nd = M - 1;
        int ft = feat0 + r; if (ft > Nc - 1) ft = Nc - 1;
        gQ[h] = A + (size_t)nd * K + qg * 8;
        gP[h] = Wt + (size_t)ft * K + qg * 8;
        lQ[h] = Qb + (size_t)(w * 64 + h * 256) * 8;
        lP[h] = Pb + (size_t)(w * 64 + h * 256) * 8;
    }

    int q4 = l >> 4, m16 = l & 15;
    int featHalf = w & 1, nodeHalf = w >> 1;
    int rP0 = featHalf * 64 + m16;
    int rQ0 = nodeHalf * 64 + m16;
    int sw = m16 & 7;

    for (int k0 = 0; k0 < K; k0 += 64) {
        __syncthreads();
#pragma unroll
        for (int h = 0; h < 4; h++) {
            stage16(gQ[h] + k0, lQ[h]);
            stage16(gP[h] + k0, lP[h]);
        }
        __syncthreads();
#pragma unroll
        for (int ko = 0; ko < 2; ko++) {
            bf16x8 pf[4], qf[4];
#pragma unroll
            for (int i = 0; i < 4; i++)
                pf[i] = *(const bf16x8*)(Pb + (rP0 + i * 16) * 64 + ((ko * 4 + q4) ^ sw) * 8);
#pragma unroll
            for (int j = 0; j < 4; j++)
                qf[j] = *(const bf16x8*)(Qb + (rQ0 + j * 16) * 64 + ((ko * 4 + q4) ^ sw) * 8);
#pragma unroll
            for (int i = 0; i < 4; i++)
#pragma unroll
                for (int j = 0; j < 4; j++)
                    acc[i][j] = __builtin_amdgcn_mfma_f32_16x16x32_bf16(pf[i], qf[j],
                                                                        acc[i][j], 0, 0, 0);
        }
    }

    // D layout: col(lane&15)=node, row(quad*4+reg)=feat -> 4 regs = 4 feats
#pragma unroll
    for (int i = 0; i < 4; i++) {
        int gf0 = feat0 + featHalf * 64 + i * 16 + q4 * 4;
        if (gf0 >= Nc) continue;
        float4 bv = make_float4(0.f, 0.f, 0.f, 0.f);
        if (doBias) bv = *(const float4*)(bias + gf0);
        size_t cb = outChunked ? ((size_t)(gf0 >> 5) * ((size_t)M * 32) + (gf0 & 31))
                               : (size_t)gf0;
#pragma unroll
        for (int j = 0; j < 4; j++) {
            int gn = node0 + nodeHalf * 64 + j * 16 + m16;
            if (gn >= M) continue;
            f32x4 v = acc[i][j];
            float x0 = v[0] + bv.x, x1 = v[1] + bv.y;
            float x2 = v[2] + bv.z, x3 = v[3] + bv.w;
            if (doRelu) {
                x0 = fmaxf(x0, 0.f); x1 = fmaxf(x1, 0.f);
                x2 = fmaxf(x2, 0.f); x3 = fmaxf(x3, 0.f);
            }
            uint2 o;
            o.x = bf16rne(x0) | (bf16rne(x1) << 16);
            o.y = bf16rne(x2) | (bf16rne(x3) << 16);
            size_t off = outChunked ? (cb + (size_t)gn * 32) : (cb + (size_t)gn * Nc);
            *(uint2*)(C + off) = o;
        }
    }
}

// out[m] = dot(A[m,0:128], w[0:128])  A bf16 row-major, one wave per row
__global__ void gemv128_bf16_kernel(const unsigned short* __restrict__ A,
                                    const float* __restrict__ w,
                                    float* __restrict__ out, int M) {
    int wid = (blockIdx.x * blockDim.x + threadIdx.x) >> 6;
    int lane = threadIdx.x & 63;
    if (wid >= M) return;
    const unsigned short* a = A + (size_t)wid * 128;
    float a0 = __uint_as_float((unsigned)a[lane] << 16);
    float a1 = __uint_as_float((unsigned)a[lane + 64] << 16);
    float s = a0 * w[lane] + a1 * w[lane + 64];
#pragma unroll
    for (int off = 32; off > 0; off >>= 1) s += __shfl_down(s, off);
    if (lane == 0) out[wid] = s;
}

// ---------------- chunked aggregation, degree-sorted, group-per-node ----------

// R12's measured-best inner loop: lane-private edge load + shfl broadcast +
// prefetch, guards on dense c. edges2 is dense sorted-node-order CSR.
__global__ __launch_bounds__(256) void agg_group_kernel(
    const uint2* __restrict__ in, const int* __restrict__ prowp2,
    const int* __restrict__ pcnt, const int* __restrict__ perm,
    const unsigned* __restrict__ edges2,
    const float* __restrict__ bias, uint2* __restrict__ out,
    int Q, int upx, int ngPerUnit, int NG, int n_nodes, int rowVec2,
    int doBias, int doRelu, int outChunked) {
    int xcd = blockIdx.x & 7;
    int slot = blockIdx.x >> 3;
    int u = slot / ngPerUnit;
    int ngIdx = slot - u * ngPerUnit;
    int unit = xcd * upx + u;
    int chunk = unit / Q;
    int q = unit - chunk * Q;
    int ng = ngIdx * Q + q;
    if (ng >= NG) return;

    int wave = threadIdx.x >> 6;
    int lane = threadIdx.x & 63;
    int group = lane >> 3, fl = lane & 7;
    int gb = lane & ~7;
    int i = ng * 32 + wave * 8 + group;        // sorted index
    if (i >= n_nodes) return;

    const uint2* slice = in + (size_t)chunk * n_nodes * 8;
    int s0 = prowp2[i];
    int c = pcnt[i] + 1;
    int node = perm[i];

    f32x2 aA[4], aB[4];
#pragma unroll
    for (int k = 0; k < 4; k++) { aA[k] = (f32x2){0.f, 0.f}; aB[k] = (f32x2){0.f, 0.f}; }

    unsigned ew = (fl < c) ? edges2[s0 + fl] : 0u;        // block 0
    for (int base = 0; base < c; base += 8) {
        int nidx = base + 8 + fl;
        unsigned ewn = (nidx < c) ? edges2[s0 + nidx] : 0u;   // prefetch next
        unsigned e[8];
#pragma unroll
        for (int j = 0; j < 8; j++) e[j] = (unsigned)__shfl((int)ew, gb + j);
        uint2 p[8];
#pragma unroll
        for (int j = 0; j < 8; j++) p[j] = slice[(int)(e[j] & 0xffffu) * 8 + fl];
#pragma unroll
        for (int j = 0; j < 8; j++) {
            float wgt = __uint_as_float(e[j] & 0xffff0000u);  // inactive: +0.0
            int k = j & 3;
            f32x2 v0 = {__uint_as_float(p[j].x << 16),
                        __uint_as_float(p[j].x & 0xffff0000u)};
            f32x2 v1 = {__uint_as_float(p[j].y << 16),
                        __uint_as_float(p[j].y & 0xffff0000u)};
            f32x2 w2 = {wgt, wgt};
            aA[k] += w2 * v0;
            aB[k] += w2 * v1;
        }
        ew = ewn;
    }
    f32x2 sA = (aA[0] + aA[1]) + (aA[2] + aA[3]);
    f32x2 sB = (aB[0] + aB[1]) + (aB[2] + aB[3]);

    if (doBias) {
        float4 bb = ((const float4*)bias)[chunk * 8 + fl];
        sA += (f32x2){bb.x, bb.y};
        sB += (f32x2){bb.z, bb.w};
    }
    if (doRelu) {
        sA[0] = fmaxf(sA[0], 0.f); sA[1] = fmaxf(sA[1], 0.f);
        sB[0] = fmaxf(sB[0], 0.f); sB[1] = fmaxf(sB[1], 0.f);
    }
    uint2 o;
    o.x = bf16rne(sA[0]) | (bf16rne(sA[1]) << 16);
    o.y = bf16rne(sB[0]) | (bf16rne(sB[1]) << 16);
    size_t oi = outChunked ? ((size_t)chunk * n_nodes * 8 + (size_t)node * 8 + fl)
                           : ((size_t)node * rowVec2 + chunk * 8 + fl);
    out[oi] = o;
}

// width-1 aggregation, fp32, sorted CSR: one thread per sorted node
__global__ void agg1_kernel(const float* __restrict__ in, const int* __restrict__ prowp2,
                            const int* __restrict__ pcnt, const int* __restrict__ perm,
                            const unsigned* __restrict__ edges2,
                            const float* __restrict__ bias, float* __restrict__ out,
                            int n_nodes) {
    int n = blockIdx.x * blockDim.x + threadIdx.x;
    if (n >= n_nodes) return;
    float acc = 0.f;
    int s0 = prowp2[n];
    int c = pcnt[n] + 1;
    for (int j = 0; j < c; j++) {
        unsigned e = edges2[s0 + j];
        acc += __uint_as_float(e & 0xffff0000u) * in[e & 0xffffu];
    }
    acc += bias[0];
    out[perm[n]] = acc;
}

// ---------------- host launcher ----------------

extern "C" void kernel_launch(void* const* d_in, const int* in_sizes, int n_in,
                              void* d_out, int out_size, void* d_ws, size_t ws_size,
                              hipStream_t stream) {
    const float* x = (const float*)d_in[0];
    const int* ei = (const int*)d_in[1];
    const int Nn = in_sizes[0] / 128;      // 50000
    const int E = in_sizes[1] / 2;         // 800000
    const int* src = ei;
    const int* dst = ei + E;

    char* ws = (char*)d_ws;
    size_t off = 0;
    auto alloc = [&](size_t bytes) -> char* {
        char* p = ws + off;
        off = (off + bytes + 255) & ~(size_t)255;
        return p;
    };
    int* cnt = (int*)alloc((size_t)Nn * 4);
    int* fill = (int*)alloc((size_t)Nn * 4);
    int* bsums = (int*)alloc(1024);
    float* dinv = (float*)alloc((size_t)Nn * 4);
    int* localRank = (int*)alloc((size_t)Nn * 4);
    int* hb = (int*)alloc((size_t)64 * 256 * 4);     // [64][nb], nb<=256
    int* perm = (int*)alloc((size_t)Nn * 4);
    int* pcnt = (int*)alloc((size_t)Nn * 4);
    int* iperm = (int*)alloc((size_t)Nn * 4);
    int* prowp2 = (int*)alloc((size_t)Nn * 4);
    unsigned* edges2 = (unsigned*)alloc((size_t)(E + Nn + 64) * 4);
    unsigned short* T = (unsigned short*)alloc((size_t)Nn * 256 * 2);
    unsigned short* H = (unsigned short*)alloc((size_t)Nn * 256 * 2);
    unsigned short* Bx = (unsigned short*)alloc((size_t)Nn * 128 * 2);
    float* F = (float*)alloc((size_t)Nn * 4);
    unsigned short* Wts = (unsigned short*)alloc((size_t)400000 * 2);
    (void)ws_size;

    const int dims[9][2] = {{128,128},{128,192},{192,256},{256,256},{256,256},
                            {256,256},{256,192},{192,128},{128,1}};
    unsigned short* Wt[8];
    {
        size_t o = 0;
        for (int i = 0; i < 8; i++) { Wt[i] = Wts + o; o += (size_t)dims[i][0] * dims[i][1]; }
    }

    int nbN = (Nn + TPB - 1) / TPB;        // 196
    int nbE = (E + TPB - 1) / TPB;
    int nbEN = (E + Nn + TPB - 1) / TPB;

    // ---- graph prep: degree sort + direct sorted dense CSR build ----
    zinit_kernel<<<nbN, TPB, 0, stream>>>(cnt, fill, Nn);
    count_kernel<<<nbE, TPB, 0, stream>>>(dst, cnt, E);
    blockhist_kernel<<<nbN, TPB, 0, stream>>>(cnt, localRank, hb, dinv, Nn, nbN);
    sortscan_kernel<<<1, 256, 0, stream>>>(hb, nbN);
    scatter2_kernel<<<nbN, TPB, 0, stream>>>(cnt, localRank, hb, perm, pcnt, iperm,
                                             Nn, nbN);
    scan1_kernel<<<nbN, TPB, 0, stream>>>(pcnt, prowp2, bsums, Nn);
    scan2_kernel<<<1, TPB, 0, stream>>>(bsums, nbN);
    scan3_kernel<<<nbN, TPB, 0, stream>>>(prowp2, bsums, Nn);
    fillself_kernel<<<nbEN, TPB, 0, stream>>>(src, dst, dinv, iperm, prowp2, fill, cnt,
                                              edges2, E, Nn);

    // ---- weight transpose (one dispatch) + input convert ----
    WPtrs wp;
    for (int i = 0; i < 8; i++) wp.p[i] = (const float*)d_in[2 + 2 * i];
    wt_all_kernel<<<(360448 + TPB - 1) / TPB, TPB, 0, stream>>>(wp, Wts);
    cvt_bf16_kernel<<<(Nn * 32 + TPB - 1) / TPB, TPB, 0, stream>>>(x, Bx, Nn * 32);

    auto gemm = [&](const unsigned short* A, int i, unsigned short* C, int K, int Nc,
                    int doBias, int doRelu, int outChunked) {
        const float* b = (const float*)d_in[3 + 2 * i];
        dim3 grid((Nn + 127) / 128, (Nc + 127) / 128);   // x: nodes, y: feats
        gemm_mfma_kernel<<<grid, 256, 0, stream>>>(A, Wt[i], b, C, Nn, K, Nc,
                                                   doBias, doRelu, outChunked);
    };
    int NG = (Nn + 31) / 32;
    auto agg = [&](const unsigned short* inb, unsigned short* outb, int w, int i,
                   int doBias, int doRelu, int outChunked) {
        int nch = w / 32;
        int Q = (nch == 8) ? 1 : (nch == 6) ? 4 : 2;     // nch*Q % 8 == 0
        int upx = nch * Q / 8;
        int ngPerUnit = (NG + Q - 1) / Q;
        int blocksPerXcd = upx * ngPerUnit;
        const float* b = (const float*)d_in[3 + 2 * i];
        agg_group_kernel<<<blocksPerXcd * 8, 256, 0, stream>>>(
            (const uint2*)inb, prowp2, pcnt, perm, edges2, b, (uint2*)outb,
            Q, upx, ngPerUnit, NG, Nn, w / 4, doBias, doRelu, outChunked);
    };

    // layout chain: GEMM in=row, out=chunked (except G2: row); agg in=chunked,
    // out=row (except A0: chunked, feeds A1)
    gemm(Bx, 0, T, 128, 128, 0, 0, 1);      // G0: t = x@W0          -> T chunked
    agg(T, H, 128, 0, 1, 1, 1);             // A0: h1 = At+b0 relu   -> H chunked
    agg(H, T, 128, 1, 0, 0, 0);             // A1: u = A h1          -> T row
    gemm(T, 1, H, 128, 192, 1, 1, 1);       // G1: h2 = u@W1+b1 relu -> H chunked
    agg(H, T, 192, 2, 0, 0, 0);             // A2: u = A h2          -> T row
    gemm(T, 2, H, 192, 256, 1, 1, 0);       // G2: h3 = u@W2+b2 relu -> H row
    gemm(H, 3, T, 256, 256, 0, 0, 1);       // G3: t = h3@W3         -> T chunked
    agg(T, H, 256, 3, 1, 1, 0);             // A3: h4 = At+b3 relu   -> H row
    gemm(H, 4, T, 256, 256, 0, 0, 1);       // G4: t = h4@W4         -> T chunked
    agg(T, H, 256, 4, 1, 0, 0);             // A4: h5 = At+b4        -> H row
    gemm(H, 5, T, 256, 256, 0, 0, 1);       // G5: t = h5@W5         -> T chunked
    agg(T, H, 256, 5, 1, 1, 0);             // A5: h6 = At+b5 relu   -> H row
    gemm(H, 6, T, 256, 192, 0, 0, 1);       // G6: t = h6@W6         -> T chunked
    agg(T, H, 192, 6, 1, 1, 0);             // A6: h7 = At+b6 relu   -> H row
    gemm(H, 7, T, 192, 128, 0, 0, 1);       // G7: t = h7@W7         -> T chunked
    agg(T, H, 128, 7, 1, 1, 0);             // A7: h8 = At+b7 relu   -> H row
    gemv128_bf16_kernel<<<(Nn + 3) / 4, 256, 0, stream>>>(H, (const float*)d_in[2 + 16],
                                                          F, Nn);
    agg1_kernel<<<nbN, TPB, 0, stream>>>(F, prowp2, pcnt, perm, edges2,
                                         (const float*)d_in[3 + 16], (float*)d_out, Nn);
}